// Round 3
// baseline (749.893 us; speedup 1.0000x reference)
//
#include <hip/hip_runtime.h>
#include <hip/hip_bf16.h>
#include <float.h>

#define NEG 0.2f

__device__ __forceinline__ float leaky(float x) { return x > 0.0f ? x : NEG * x; }

__device__ __forceinline__ unsigned short f2bf(float f) {
  unsigned x = __float_as_uint(f);
  unsigned r = (x + 0x7fffu + ((x >> 16) & 1u)) >> 16;  // round-to-nearest-even
  return (unsigned short)r;
}

__device__ __forceinline__ float2 bf2f2(unsigned u) {   // u = (ch1<<16)|ch0
  float2 r;
  r.x = __uint_as_float(u << 16);
  r.y = __uint_as_float(u & 0xffff0000u);
  return r;
}

// ---------------------------------------------------------------- utilities
__global__ void zero_kernel(int* __restrict__ p, int n) {
  int i = blockIdx.x * blockDim.x + threadIdx.x;
  int stride = gridDim.x * blockDim.x;
  for (; i < n; i += stride) p[i] = 0;
}

__global__ void count_kernel(const int* __restrict__ ei, int* __restrict__ deg, int E, int N) {
  int i = blockIdx.x * blockDim.x + threadIdx.x;
  if (i >= E + N) return;
  int dst = (i < E) ? ei[E + i] : (i - E);
  atomicAdd(&deg[dst], 1);
}

__global__ __launch_bounds__(1024) void scan_block_kernel(const int* __restrict__ deg,
                                                          int* __restrict__ row_start,
                                                          int* __restrict__ sums, int n) {
  __shared__ int buf[1024];
  int t = threadIdx.x;
  int idx = blockIdx.x * 1024 + t;
  int x = (idx < n) ? deg[idx] : 0;
  int v = x;
  buf[t] = v;
  __syncthreads();
  for (int off = 1; off < 1024; off <<= 1) {
    int a = (t >= off) ? buf[t - off] : 0;
    __syncthreads();
    v += a;
    buf[t] = v;
    __syncthreads();
  }
  if (idx < n) row_start[idx] = v - x;  // local exclusive
  if (t == 1023) sums[blockIdx.x] = v;  // chunk total
}

__global__ __launch_bounds__(1024) void scan_sums_kernel(int* __restrict__ sums,
                                                         int* __restrict__ row_start,
                                                         int nch, int n) {
  __shared__ int buf[1024];
  int t = threadIdx.x;
  int x = (t < nch) ? sums[t] : 0;
  int v = x;
  buf[t] = v;
  __syncthreads();
  for (int off = 1; off < 1024; off <<= 1) {
    int a = (t >= off) ? buf[t - off] : 0;
    __syncthreads();
    v += a;
    buf[t] = v;
    __syncthreads();
  }
  if (t < nch) sums[t] = v - x;        // exclusive chunk offsets
  if (t == 1023) row_start[n] = v;     // grand total
}

__global__ __launch_bounds__(1024) void scan_add_kernel(int* __restrict__ row_start,
                                                        const int* __restrict__ sums, int n) {
  int idx = blockIdx.x * 1024 + threadIdx.x;
  if (idx < n) row_start[idx] += sums[blockIdx.x];
}

__global__ void fill_kernel(const int* __restrict__ ei, int* __restrict__ cursor,
                            const int* __restrict__ row_start, int* __restrict__ csr_src,
                            int E, int N) {
  int i = blockIdx.x * blockDim.x + threadIdx.x;
  if (i >= E + N) return;
  int src, dst;
  if (i < E) { src = ei[i]; dst = ei[E + i]; } else { src = dst = i - E; }
  int pos = atomicAdd(&cursor[dst], 1);
  csr_src[row_start[dst] + pos] = src;
}

// ---------------------------------------------------------------- GEMM  Hb = bf16(X @ W), fused alpha dots
__global__ __launch_bounds__(256) void gemm_kernel(const float* __restrict__ X,
                                                   const float* __restrict__ W,
                                                   unsigned short* __restrict__ Hb,
                                                   const float* __restrict__ a_src,
                                                   const float* __restrict__ a_dst,
                                                   float* __restrict__ as_arr,
                                                   float* __restrict__ ad_arr,
                                                   int nrows, int K) {
  __shared__ float Xs[64][36];    // 64 rows x 32 k, stride 36
  __shared__ float Ws[32][132];   // 32 k x 128 cols, stride 132
  int t = threadIdx.x;
  int row0 = blockIdx.x * 64;
  int tcol = t & 31;   // 32 col-groups of 4 cols
  int trow = t >> 5;   // 8 row-groups; rows trow + 8*i
  float acc[8][4];
#pragma unroll
  for (int i = 0; i < 8; ++i)
#pragma unroll
    for (int j = 0; j < 4; ++j) acc[i][j] = 0.0f;

  for (int kb = 0; kb < K; kb += 32) {
#pragma unroll
    for (int p = 0; p < 2; ++p) {       // X tile: 64x32 = 512 float4
      int flat = t + p * 256;
      int r = flat >> 3;
      int kq = (flat & 7) * 4;
      float4 v = make_float4(0.f, 0.f, 0.f, 0.f);
      int gr = row0 + r;
      if (gr < nrows) v = *(const float4*)(X + (size_t)gr * K + kb + kq);
      *(float4*)(&Xs[r][kq]) = v;
    }
#pragma unroll
    for (int p = 0; p < 4; ++p) {       // W tile: 32x128 = 1024 float4
      int flat = t + p * 256;
      int r = flat >> 5;
      int cq = (flat & 31) * 4;
      float4 v = *(const float4*)(W + (size_t)(kb + r) * 128 + cq);
      *(float4*)(&Ws[r][cq]) = v;
    }
    __syncthreads();
#pragma unroll
    for (int kk = 0; kk < 32; kk += 4) {
      float4 xv[8];
#pragma unroll
      for (int i = 0; i < 8; ++i) xv[i] = *(const float4*)(&Xs[trow + 8 * i][kk]);
#pragma unroll
      for (int q = 0; q < 4; ++q) {
        float4 wv = *(const float4*)(&Ws[kk + q][tcol * 4]);
#pragma unroll
        for (int i = 0; i < 8; ++i) {
          float xq = (q == 0) ? xv[i].x : (q == 1) ? xv[i].y : (q == 2) ? xv[i].z : xv[i].w;
          acc[i][0] += xq * wv.x;
          acc[i][1] += xq * wv.y;
          acc[i][2] += xq * wv.z;
          acc[i][3] += xq * wv.w;
        }
      }
    }
    __syncthreads();
  }

  // store bf16 H + fused per-head alpha dots
  float4 as4 = *(const float4*)(a_src + tcol * 4);
  float4 ad4 = *(const float4*)(a_dst + tcol * 4);
  float ps[8], pd[8];
#pragma unroll
  for (int i = 0; i < 8; ++i) {
    int r = row0 + trow + 8 * i;
    if (r < nrows) {
      union { unsigned short u[4]; uint2 v; } pk;
      pk.u[0] = f2bf(acc[i][0]);
      pk.u[1] = f2bf(acc[i][1]);
      pk.u[2] = f2bf(acc[i][2]);
      pk.u[3] = f2bf(acc[i][3]);
      *(uint2*)(Hb + (size_t)r * 128 + tcol * 4) = pk.v;
    }
    ps[i] = acc[i][0] * as4.x + acc[i][1] * as4.y + acc[i][2] * as4.z + acc[i][3] * as4.w;
    pd[i] = acc[i][0] * ad4.x + acc[i][1] * ad4.y + acc[i][2] * ad4.z + acc[i][3] * ad4.w;
  }
#pragma unroll
  for (int off = 1; off < 8; off <<= 1) {
#pragma unroll
    for (int i = 0; i < 8; ++i) {
      ps[i] += __shfl_xor(ps[i], off);
      pd[i] += __shfl_xor(pd[i], off);
    }
  }
  if ((tcol & 7) == 0) {
    int head = tcol >> 3;
#pragma unroll
    for (int i = 0; i < 8; ++i) {
      int r = row0 + trow + 8 * i;
      if (r < nrows) {
        as_arr[(size_t)r * 4 + head] = ps[i];
        ad_arr[(size_t)r * 4 + head] = pd[i];
      }
    }
  }
}

// ---------------------------------------------------------------- aggregation v3
// one wave per dst node; 4 edges per round (16 lanes/row, dwordx4 gather);
// per-64-edge prefetch of idx + exp(leaky(logit)) for all 4 heads into wave-private LDS.
template <int POOL>
__global__ __launch_bounds__(256) void agg_kernel(const unsigned short* __restrict__ Hb,
                                                  const float* __restrict__ as_arr,
                                                  const float* __restrict__ ad_arr,
                                                  const int* __restrict__ csr_src,
                                                  const int* __restrict__ row_start,
                                                  const float* __restrict__ bias,
                                                  float* __restrict__ xnext,
                                                  const int* __restrict__ batch,
                                                  float* __restrict__ pooled, int N) {
  __shared__ float eL[4][64][4];   // [wave][edge-slot][head]
  __shared__ int iL[4][64];        // [wave][edge-slot] src index
  int wid = threadIdx.x >> 6;
  int lane = threadIdx.x & 63;
  int q = lane >> 4;      // quarter: which edge of the round
  int ql = lane & 15;     // position in quarter: owns channels 8*ql..8*ql+7
  int h = ql >> 2;        // head of those channels
  int n = blockIdx.x * 4 + wid;
  if (n >= N) return;
  int rs = row_start[n], re = row_start[n + 1];
  int deg = re - rs;
  float4 adn = *(const float4*)(ad_arr + (size_t)n * 4);

  float acc[8];
#pragma unroll
  for (int j = 0; j < 8; ++j) acc[j] = 0.f;
  float denom = 0.f;

  for (int base = 0; base < deg; base += 64) {
    // prefetch phase: 64 edges' idx + all-head exp values
    int pos = rs + base + lane;
    int idx = 0;
    float4 e4 = make_float4(0.f, 0.f, 0.f, 0.f);
    if (pos < re) {
      idx = csr_src[pos];
      float4 a4 = *(const float4*)(as_arr + (size_t)idx * 4);
      e4.x = __expf(fminf(leaky(a4.x + adn.x), 80.f));
      e4.y = __expf(fminf(leaky(a4.y + adn.y), 80.f));
      e4.z = __expf(fminf(leaky(a4.z + adn.z), 80.f));
      e4.w = __expf(fminf(leaky(a4.w + adn.w), 80.f));
    }
    iL[wid][lane] = idx;
    *(float4*)(&eL[wid][lane][0]) = e4;
    // wave-private LDS, in-order per wave -> no barrier needed

    int nr = deg - base; if (nr > 64) nr = 64;
    int rounds = (nr + 3) >> 2;
    for (int r = 0; r < rounds; ++r) {
      int sl = 4 * r + q;
      float ex = eL[wid][sl][h];           // 0 for invalid tail slots
      int s = iL[wid][sl];                 // 0 for invalid (row 0: L1-hot)
      uint4 u = *(const uint4*)(Hb + ((size_t)s << 7) + (ql << 3));
      float2 f;
      f = bf2f2(u.x); acc[0] += ex * f.x; acc[1] += ex * f.y;
      f = bf2f2(u.y); acc[2] += ex * f.x; acc[3] += ex * f.y;
      f = bf2f2(u.z); acc[4] += ex * f.x; acc[5] += ex * f.y;
      f = bf2f2(u.w); acc[6] += ex * f.x; acc[7] += ex * f.y;
      denom += ex;
    }
  }

  // combine the 4 quarters (same ql across quarters -> same channels)
#pragma unroll
  for (int off = 16; off <= 32; off <<= 1) {
#pragma unroll
    for (int j = 0; j < 8; ++j) acc[j] += __shfl_xor(acc[j], off);
    denom += __shfl_xor(denom, off);
  }

  if (q == 0) {
    float inv = 1.0f / (denom + 1e-16f);
    float4 b0 = *(const float4*)(bias + ql * 8);
    float4 b1 = *(const float4*)(bias + ql * 8 + 4);
    float v0 = leaky(acc[0] * inv + b0.x);
    float v1 = leaky(acc[1] * inv + b0.y);
    float v2 = leaky(acc[2] * inv + b0.z);
    float v3 = leaky(acc[3] * inv + b0.w);
    float v4 = leaky(acc[4] * inv + b1.x);
    float v5 = leaky(acc[5] * inv + b1.y);
    float v6 = leaky(acc[6] * inv + b1.z);
    float v7 = leaky(acc[7] * inv + b1.w);
    if (POOL) {
      int g = batch[n];
      float* pp = pooled + (size_t)g * 128 + ql * 8;
      atomicAdd(pp + 0, v0); atomicAdd(pp + 1, v1);
      atomicAdd(pp + 2, v2); atomicAdd(pp + 3, v3);
      atomicAdd(pp + 4, v4); atomicAdd(pp + 5, v5);
      atomicAdd(pp + 6, v6); atomicAdd(pp + 7, v7);
    } else {
      float* xp = xnext + (size_t)n * 128 + ql * 8;
      *(float4*)(xp + 0) = make_float4(v0, v1, v2, v3);
      *(float4*)(xp + 4) = make_float4(v4, v5, v6, v7);
    }
  }
}

// ---------------------------------------------------------------- head
__global__ void head_kernel(const float* __restrict__ pooled, const float* __restrict__ fc_w,
                            const float* __restrict__ fc_b, const float* __restrict__ bn_g,
                            const float* __restrict__ bn_b, float* __restrict__ out, int G) {
  int t = threadIdx.x;
  int g = blockIdx.x * 8 + (t >> 5);
  int j = t & 31;
  if (g >= G) return;
  const float* pr = pooled + (size_t)g * 128;
  float acc = 0.f;
#pragma unroll 8
  for (int k = 0; k < 128; ++k) acc += pr[k] * fc_w[k * 32 + j];
  const float inv = 0.9999950000374997f;  // 1/sqrt(1+1e-5)
  out[g * 32 + j] = bn_g[j] * (acc + fc_b[j]) * inv + bn_b[j];
}

// ---------------------------------------------------------------- launch
extern "C" void kernel_launch(void* const* d_in, const int* in_sizes, int n_in,
                              void* d_out, int out_size, void* d_ws, size_t ws_size,
                              hipStream_t stream) {
  const float* x = (const float*)d_in[0];
  const int* ei = (const int*)d_in[1];
  const int* batch = (const int*)d_in[2];
  const float* Wm[3] = {(const float*)d_in[3], (const float*)d_in[7], (const float*)d_in[11]};
  const float* a_s[3] = {(const float*)d_in[4], (const float*)d_in[8], (const float*)d_in[12]};
  const float* a_d[3] = {(const float*)d_in[5], (const float*)d_in[9], (const float*)d_in[13]};
  const float* bb[3] = {(const float*)d_in[6], (const float*)d_in[10], (const float*)d_in[14]};
  const float* fc_w = (const float*)d_in[15];
  const float* fc_b = (const float*)d_in[16];
  const float* bn_g = (const float*)d_in[17];
  const float* bn_b = (const float*)d_in[18];
  float* out = (float*)d_out;

  int N = in_sizes[0] / 64;
  int E = in_sizes[1] / 2;
  int G = out_size / 32;
  int Etot = E + N;

  char* p = (char*)d_ws;
  auto carve = [&](size_t bytes) {
    char* r = p;
    p += (bytes + 255) & ~size_t(255);
    return r;
  };
  int* deg       = (int*)carve((size_t)N * 4);
  int* cursor    = (int*)carve((size_t)N * 4);
  float* pooled  = (float*)carve((size_t)G * 128 * 4);
  int* row_start = (int*)carve((size_t)(N + 1) * 4);
  int* sums      = (int*)carve(4096);
  int* csr_src   = (int*)carve((size_t)Etot * 4);
  unsigned short* Hb = (unsigned short*)carve((size_t)N * 128 * 2);  // bf16 features
  float* bufX    = (float*)carve((size_t)N * 128 * 4);               // fp32 layer input
  float* as_arr  = (float*)carve((size_t)N * 4 * 4);
  float* ad_arr  = (float*)carve((size_t)N * 4 * 4);

  // zero deg+cursor+pooled (contiguous carve region, pads included)
  int nz = (int)(((char*)(pooled + (size_t)G * 128) - (char*)deg) / 4);
  zero_kernel<<<512, 256, 0, stream>>>(deg, nz);

  // CSR build (dst-grouped)
  int egrid = (Etot + 255) / 256;
  count_kernel<<<egrid, 256, 0, stream>>>(ei, deg, E, N);
  int nch = (N + 1023) / 1024;
  scan_block_kernel<<<nch, 1024, 0, stream>>>(deg, row_start, sums, N);
  scan_sums_kernel<<<1, 1024, 0, stream>>>(sums, row_start, nch, N);
  scan_add_kernel<<<nch, 1024, 0, stream>>>(row_start, sums, N);
  fill_kernel<<<egrid, 256, 0, stream>>>(ei, cursor, row_start, csr_src, E, N);

  int ggrid = (N + 63) / 64;
  int ngrid = (N + 3) / 4;

  // layer 0 (K=64)
  gemm_kernel<<<ggrid, 256, 0, stream>>>(x, Wm[0], Hb, a_s[0], a_d[0], as_arr, ad_arr, N, 64);
  agg_kernel<0><<<ngrid, 256, 0, stream>>>(Hb, as_arr, ad_arr, csr_src, row_start, bb[0],
                                           bufX, nullptr, nullptr, N);
  // layer 1 (K=128)
  gemm_kernel<<<ggrid, 256, 0, stream>>>(bufX, Wm[1], Hb, a_s[1], a_d[1], as_arr, ad_arr, N, 128);
  agg_kernel<0><<<ngrid, 256, 0, stream>>>(Hb, as_arr, ad_arr, csr_src, row_start, bb[1],
                                           bufX, nullptr, nullptr, N);
  // layer 2 (K=128), fused pooling
  gemm_kernel<<<ggrid, 256, 0, stream>>>(bufX, Wm[2], Hb, a_s[2], a_d[2], as_arr, ad_arr, N, 128);
  agg_kernel<1><<<ngrid, 256, 0, stream>>>(Hb, as_arr, ad_arr, csr_src, row_start, bb[2],
                                           nullptr, batch, pooled, N);

  head_kernel<<<(G + 7) / 8, 256, 0, stream>>>(pooled, fc_w, fc_b, bn_g, bn_b, out, G);
}

// Round 4
// 666.541 us; speedup vs baseline: 1.1251x; 1.1251x over previous
//
#include <hip/hip_runtime.h>
#include <hip/hip_bf16.h>
#include <float.h>

#define NEG 0.2f

__device__ __forceinline__ float leaky(float x) { return x > 0.0f ? x : NEG * x; }

__device__ __forceinline__ unsigned short f2bf(float f) {
  unsigned x = __float_as_uint(f);
  unsigned r = (x + 0x7fffu + ((x >> 16) & 1u)) >> 16;  // round-to-nearest-even
  return (unsigned short)r;
}

__device__ __forceinline__ float2 bf2f2(unsigned u) {   // u = (ch1<<16)|ch0
  float2 r;
  r.x = __uint_as_float(u << 16);
  r.y = __uint_as_float(u & 0xffff0000u);
  return r;
}

// ---------------------------------------------------------------- utilities
__global__ void zero_kernel(int* __restrict__ p, int n) {
  int i = blockIdx.x * blockDim.x + threadIdx.x;
  int stride = gridDim.x * blockDim.x;
  for (; i < n; i += stride) p[i] = 0;
}

__global__ void count_kernel(const int* __restrict__ ei, int* __restrict__ deg, int E, int N) {
  int i = blockIdx.x * blockDim.x + threadIdx.x;
  if (i >= E + N) return;
  int dst = (i < E) ? ei[E + i] : (i - E);
  atomicAdd(&deg[dst], 1);
}

__global__ __launch_bounds__(1024) void scan_block_kernel(const int* __restrict__ deg,
                                                          int* __restrict__ row_start,
                                                          int* __restrict__ sums, int n) {
  __shared__ int buf[1024];
  int t = threadIdx.x;
  int idx = blockIdx.x * 1024 + t;
  int x = (idx < n) ? deg[idx] : 0;
  int v = x;
  buf[t] = v;
  __syncthreads();
  for (int off = 1; off < 1024; off <<= 1) {
    int a = (t >= off) ? buf[t - off] : 0;
    __syncthreads();
    v += a;
    buf[t] = v;
    __syncthreads();
  }
  if (idx < n) row_start[idx] = v - x;  // local exclusive
  if (t == 1023) sums[blockIdx.x] = v;  // chunk total
}

__global__ __launch_bounds__(1024) void scan_sums_kernel(int* __restrict__ sums,
                                                         int* __restrict__ row_start,
                                                         int nch, int n) {
  __shared__ int buf[1024];
  int t = threadIdx.x;
  int x = (t < nch) ? sums[t] : 0;
  int v = x;
  buf[t] = v;
  __syncthreads();
  for (int off = 1; off < 1024; off <<= 1) {
    int a = (t >= off) ? buf[t - off] : 0;
    __syncthreads();
    v += a;
    buf[t] = v;
    __syncthreads();
  }
  if (t < nch) sums[t] = v - x;        // exclusive chunk offsets
  if (t == 1023) row_start[n] = v;     // grand total
}

__global__ __launch_bounds__(1024) void scan_add_kernel(int* __restrict__ row_start,
                                                        const int* __restrict__ sums, int n) {
  int idx = blockIdx.x * 1024 + threadIdx.x;
  if (idx < n) row_start[idx] += sums[blockIdx.x];
}

__global__ void fill_kernel(const int* __restrict__ ei, int* __restrict__ cursor,
                            const int* __restrict__ row_start, int* __restrict__ csr_src,
                            int E, int N) {
  int i = blockIdx.x * blockDim.x + threadIdx.x;
  if (i >= E + N) return;
  int src, dst;
  if (i < E) { src = ei[i]; dst = ei[E + i]; } else { src = dst = i - E; }
  int pos = atomicAdd(&cursor[dst], 1);
  csr_src[row_start[dst] + pos] = src;
}

// ---------------------------------------------------------------- GEMM  Hb = bf16(X @ W), fused alpha dots
__global__ __launch_bounds__(256) void gemm_kernel(const float* __restrict__ X,
                                                   const float* __restrict__ W,
                                                   unsigned short* __restrict__ Hb,
                                                   const float* __restrict__ a_src,
                                                   const float* __restrict__ a_dst,
                                                   float* __restrict__ as_arr,
                                                   float* __restrict__ ad_arr,
                                                   int nrows, int K) {
  __shared__ float Xs[64][36];    // 64 rows x 32 k, stride 36
  __shared__ float Ws[32][132];   // 32 k x 128 cols, stride 132
  int t = threadIdx.x;
  int row0 = blockIdx.x * 64;
  int tcol = t & 31;   // 32 col-groups of 4 cols
  int trow = t >> 5;   // 8 row-groups; rows trow + 8*i
  float acc[8][4];
#pragma unroll
  for (int i = 0; i < 8; ++i)
#pragma unroll
    for (int j = 0; j < 4; ++j) acc[i][j] = 0.0f;

  for (int kb = 0; kb < K; kb += 32) {
#pragma unroll
    for (int p = 0; p < 2; ++p) {       // X tile: 64x32 = 512 float4
      int flat = t + p * 256;
      int r = flat >> 3;
      int kq = (flat & 7) * 4;
      float4 v = make_float4(0.f, 0.f, 0.f, 0.f);
      int gr = row0 + r;
      if (gr < nrows) v = *(const float4*)(X + (size_t)gr * K + kb + kq);
      *(float4*)(&Xs[r][kq]) = v;
    }
#pragma unroll
    for (int p = 0; p < 4; ++p) {       // W tile: 32x128 = 1024 float4
      int flat = t + p * 256;
      int r = flat >> 5;
      int cq = (flat & 31) * 4;
      float4 v = *(const float4*)(W + (size_t)(kb + r) * 128 + cq);
      *(float4*)(&Ws[r][cq]) = v;
    }
    __syncthreads();
#pragma unroll
    for (int kk = 0; kk < 32; kk += 4) {
      float4 xv[8];
#pragma unroll
      for (int i = 0; i < 8; ++i) xv[i] = *(const float4*)(&Xs[trow + 8 * i][kk]);
#pragma unroll
      for (int q = 0; q < 4; ++q) {
        float4 wv = *(const float4*)(&Ws[kk + q][tcol * 4]);
#pragma unroll
        for (int i = 0; i < 8; ++i) {
          float xq = (q == 0) ? xv[i].x : (q == 1) ? xv[i].y : (q == 2) ? xv[i].z : xv[i].w;
          acc[i][0] += xq * wv.x;
          acc[i][1] += xq * wv.y;
          acc[i][2] += xq * wv.z;
          acc[i][3] += xq * wv.w;
        }
      }
    }
    __syncthreads();
  }

  // store bf16 H + fused per-head alpha dots
  float4 as4 = *(const float4*)(a_src + tcol * 4);
  float4 ad4 = *(const float4*)(a_dst + tcol * 4);
  float ps[8], pd[8];
#pragma unroll
  for (int i = 0; i < 8; ++i) {
    int r = row0 + trow + 8 * i;
    if (r < nrows) {
      union { unsigned short u[4]; uint2 v; } pk;
      pk.u[0] = f2bf(acc[i][0]);
      pk.u[1] = f2bf(acc[i][1]);
      pk.u[2] = f2bf(acc[i][2]);
      pk.u[3] = f2bf(acc[i][3]);
      *(uint2*)(Hb + (size_t)r * 128 + tcol * 4) = pk.v;
    }
    ps[i] = acc[i][0] * as4.x + acc[i][1] * as4.y + acc[i][2] * as4.z + acc[i][3] * as4.w;
    pd[i] = acc[i][0] * ad4.x + acc[i][1] * ad4.y + acc[i][2] * ad4.z + acc[i][3] * ad4.w;
  }
#pragma unroll
  for (int off = 1; off < 8; off <<= 1) {
#pragma unroll
    for (int i = 0; i < 8; ++i) {
      ps[i] += __shfl_xor(ps[i], off);
      pd[i] += __shfl_xor(pd[i], off);
    }
  }
  if ((tcol & 7) == 0) {
    int head = tcol >> 3;
#pragma unroll
    for (int i = 0; i < 8; ++i) {
      int r = row0 + trow + 8 * i;
      if (r < nrows) {
        as_arr[(size_t)r * 4 + head] = ps[i];
        ad_arr[(size_t)r * 4 + head] = pd[i];
      }
    }
  }
}

// ---------------------------------------------------------------- aggregation v4
// one QUARTER-wave (16 lanes) per dst node; lane ql owns 8 channels (16B bf16 uint4).
// 4 nodes per wave -> each VMEM instr carries 4 edges; unroll-2 -> 8 independent
// gather chains per wave. No LDS, no cross-lane reduction (denom replicated in quarter).
template <int POOL>
__global__ __launch_bounds__(256) void agg_kernel(const unsigned short* __restrict__ Hb,
                                                  const float* __restrict__ as_arr,
                                                  const float* __restrict__ ad_arr,
                                                  const int* __restrict__ csr_src,
                                                  const int* __restrict__ row_start,
                                                  const float* __restrict__ bias,
                                                  float* __restrict__ xnext,
                                                  const int* __restrict__ batch,
                                                  float* __restrict__ pooled, int N) {
  int t = threadIdx.x;
  int lane = t & 63, wav = t >> 6;
  int q = lane >> 4, ql = lane & 15, h = ql >> 2;
  int n = blockIdx.x * 16 + wav * 4 + q;
  if (n >= N) return;
  int rs = row_start[n], re = row_start[n + 1];
  float ad_h = ad_arr[(size_t)n * 4 + h];
  const uint4* hb4 = (const uint4*)Hb;  // row = 16 uint4

  float acc[8];
#pragma unroll
  for (int j = 0; j < 8; ++j) acc[j] = 0.f;
  float denom = 0.f;

  int i = rs;
  for (; i + 2 <= re; i += 2) {
    int s0 = csr_src[i], s1 = csr_src[i + 1];
    float a0 = as_arr[(size_t)s0 * 4 + h];
    float a1 = as_arr[(size_t)s1 * 4 + h];
    uint4 u0 = hb4[(size_t)s0 * 16 + ql];
    uint4 u1 = hb4[(size_t)s1 * 16 + ql];
    float e0 = __expf(fminf(leaky(a0 + ad_h), 80.f));
    float e1 = __expf(fminf(leaky(a1 + ad_h), 80.f));
    denom += e0 + e1;
    float2 f;
    f = bf2f2(u0.x); acc[0] += e0 * f.x; acc[1] += e0 * f.y;
    f = bf2f2(u0.y); acc[2] += e0 * f.x; acc[3] += e0 * f.y;
    f = bf2f2(u0.z); acc[4] += e0 * f.x; acc[5] += e0 * f.y;
    f = bf2f2(u0.w); acc[6] += e0 * f.x; acc[7] += e0 * f.y;
    f = bf2f2(u1.x); acc[0] += e1 * f.x; acc[1] += e1 * f.y;
    f = bf2f2(u1.y); acc[2] += e1 * f.x; acc[3] += e1 * f.y;
    f = bf2f2(u1.z); acc[4] += e1 * f.x; acc[5] += e1 * f.y;
    f = bf2f2(u1.w); acc[6] += e1 * f.x; acc[7] += e1 * f.y;
  }
  if (i < re) {
    int s0 = csr_src[i];
    float a0 = as_arr[(size_t)s0 * 4 + h];
    uint4 u0 = hb4[(size_t)s0 * 16 + ql];
    float e0 = __expf(fminf(leaky(a0 + ad_h), 80.f));
    denom += e0;
    float2 f;
    f = bf2f2(u0.x); acc[0] += e0 * f.x; acc[1] += e0 * f.y;
    f = bf2f2(u0.y); acc[2] += e0 * f.x; acc[3] += e0 * f.y;
    f = bf2f2(u0.z); acc[4] += e0 * f.x; acc[5] += e0 * f.y;
    f = bf2f2(u0.w); acc[6] += e0 * f.x; acc[7] += e0 * f.y;
  }

  float inv = 1.0f / (denom + 1e-16f);
  float4 b0 = *(const float4*)(bias + ql * 8);
  float4 b1 = *(const float4*)(bias + ql * 8 + 4);
  float v0 = leaky(acc[0] * inv + b0.x);
  float v1 = leaky(acc[1] * inv + b0.y);
  float v2 = leaky(acc[2] * inv + b0.z);
  float v3 = leaky(acc[3] * inv + b0.w);
  float v4 = leaky(acc[4] * inv + b1.x);
  float v5 = leaky(acc[5] * inv + b1.y);
  float v6 = leaky(acc[6] * inv + b1.z);
  float v7 = leaky(acc[7] * inv + b1.w);
  if (POOL) {
    int g = batch[n];
    float* pp = pooled + (size_t)g * 128 + ql * 8;
    atomicAdd(pp + 0, v0); atomicAdd(pp + 1, v1);
    atomicAdd(pp + 2, v2); atomicAdd(pp + 3, v3);
    atomicAdd(pp + 4, v4); atomicAdd(pp + 5, v5);
    atomicAdd(pp + 6, v6); atomicAdd(pp + 7, v7);
  } else {
    float* xp = xnext + (size_t)n * 128 + ql * 8;
    *(float4*)(xp + 0) = make_float4(v0, v1, v2, v3);
    *(float4*)(xp + 4) = make_float4(v4, v5, v6, v7);
  }
}

// ---------------------------------------------------------------- head
__global__ void head_kernel(const float* __restrict__ pooled, const float* __restrict__ fc_w,
                            const float* __restrict__ fc_b, const float* __restrict__ bn_g,
                            const float* __restrict__ bn_b, float* __restrict__ out, int G) {
  int t = threadIdx.x;
  int g = blockIdx.x * 8 + (t >> 5);
  int j = t & 31;
  if (g >= G) return;
  const float* pr = pooled + (size_t)g * 128;
  float acc = 0.f;
#pragma unroll 8
  for (int k = 0; k < 128; ++k) acc += pr[k] * fc_w[k * 32 + j];
  const float inv = 0.9999950000374997f;  // 1/sqrt(1+1e-5)
  out[g * 32 + j] = bn_g[j] * (acc + fc_b[j]) * inv + bn_b[j];
}

// ---------------------------------------------------------------- launch
extern "C" void kernel_launch(void* const* d_in, const int* in_sizes, int n_in,
                              void* d_out, int out_size, void* d_ws, size_t ws_size,
                              hipStream_t stream) {
  const float* x = (const float*)d_in[0];
  const int* ei = (const int*)d_in[1];
  const int* batch = (const int*)d_in[2];
  const float* Wm[3] = {(const float*)d_in[3], (const float*)d_in[7], (const float*)d_in[11]};
  const float* a_s[3] = {(const float*)d_in[4], (const float*)d_in[8], (const float*)d_in[12]};
  const float* a_d[3] = {(const float*)d_in[5], (const float*)d_in[9], (const float*)d_in[13]};
  const float* bb[3] = {(const float*)d_in[6], (const float*)d_in[10], (const float*)d_in[14]};
  const float* fc_w = (const float*)d_in[15];
  const float* fc_b = (const float*)d_in[16];
  const float* bn_g = (const float*)d_in[17];
  const float* bn_b = (const float*)d_in[18];
  float* out = (float*)d_out;

  int N = in_sizes[0] / 64;
  int E = in_sizes[1] / 2;
  int G = out_size / 32;
  int Etot = E + N;

  char* p = (char*)d_ws;
  auto carve = [&](size_t bytes) {
    char* r = p;
    p += (bytes + 255) & ~size_t(255);
    return r;
  };
  int* deg       = (int*)carve((size_t)N * 4);
  int* cursor    = (int*)carve((size_t)N * 4);
  float* pooled  = (float*)carve((size_t)G * 128 * 4);
  int* row_start = (int*)carve((size_t)(N + 1) * 4);
  int* sums      = (int*)carve(4096);
  int* csr_src   = (int*)carve((size_t)Etot * 4);
  unsigned short* Hb = (unsigned short*)carve((size_t)N * 128 * 2);  // bf16 features
  float* bufX    = (float*)carve((size_t)N * 128 * 4);               // fp32 layer input
  float* as_arr  = (float*)carve((size_t)N * 4 * 4);
  float* ad_arr  = (float*)carve((size_t)N * 4 * 4);

  // zero deg+cursor+pooled (contiguous carve region, pads included)
  int nz = (int)(((char*)(pooled + (size_t)G * 128) - (char*)deg) / 4);
  zero_kernel<<<512, 256, 0, stream>>>(deg, nz);

  // CSR build (dst-grouped)
  int egrid = (Etot + 255) / 256;
  count_kernel<<<egrid, 256, 0, stream>>>(ei, deg, E, N);
  int nch = (N + 1023) / 1024;
  scan_block_kernel<<<nch, 1024, 0, stream>>>(deg, row_start, sums, N);
  scan_sums_kernel<<<1, 1024, 0, stream>>>(sums, row_start, nch, N);
  scan_add_kernel<<<nch, 1024, 0, stream>>>(row_start, sums, N);
  fill_kernel<<<egrid, 256, 0, stream>>>(ei, cursor, row_start, csr_src, E, N);

  int ggrid = (N + 63) / 64;
  int ngrid = (N + 15) / 16;   // 16 nodes per block (4 waves x 4 quarters)

  // layer 0 (K=64)
  gemm_kernel<<<ggrid, 256, 0, stream>>>(x, Wm[0], Hb, a_s[0], a_d[0], as_arr, ad_arr, N, 64);
  agg_kernel<0><<<ngrid, 256, 0, stream>>>(Hb, as_arr, ad_arr, csr_src, row_start, bb[0],
                                           bufX, nullptr, nullptr, N);
  // layer 1 (K=128)
  gemm_kernel<<<ggrid, 256, 0, stream>>>(bufX, Wm[1], Hb, a_s[1], a_d[1], as_arr, ad_arr, N, 128);
  agg_kernel<0><<<ngrid, 256, 0, stream>>>(Hb, as_arr, ad_arr, csr_src, row_start, bb[1],
                                           bufX, nullptr, nullptr, N);
  // layer 2 (K=128), fused pooling
  gemm_kernel<<<ggrid, 256, 0, stream>>>(bufX, Wm[2], Hb, a_s[2], a_d[2], as_arr, ad_arr, N, 128);
  agg_kernel<1><<<ngrid, 256, 0, stream>>>(Hb, as_arr, ad_arr, csr_src, row_start, bb[2],
                                           nullptr, batch, pooled, N);

  head_kernel<<<(G + 7) / 8, 256, 0, stream>>>(pooled, fc_w, fc_b, bn_g, bn_b, out, G);
}

// Round 5
// 483.096 us; speedup vs baseline: 1.5523x; 1.3797x over previous
//
#include <hip/hip_runtime.h>
#include <hip/hip_bf16.h>
#include <float.h>

#define NEG 0.2f

__device__ __forceinline__ float leaky(float x) { return x > 0.0f ? x : NEG * x; }

__device__ __forceinline__ unsigned short f2bf(float f) {
  unsigned x = __float_as_uint(f);
  unsigned r = (x + 0x7fffu + ((x >> 16) & 1u)) >> 16;  // round-to-nearest-even
  return (unsigned short)r;
}

__device__ __forceinline__ float2 bf2f2(unsigned u) {   // u = (ch1<<16)|ch0
  float2 r;
  r.x = __uint_as_float(u << 16);
  r.y = __uint_as_float(u & 0xffff0000u);
  return r;
}

// ---------------------------------------------------------------- utilities
__global__ void zero_kernel(int* __restrict__ p, int n) {
  int i = blockIdx.x * blockDim.x + threadIdx.x;
  int stride = gridDim.x * blockDim.x;
  for (; i < n; i += stride) p[i] = 0;
}

__global__ void count_kernel(const int* __restrict__ ei, int* __restrict__ deg, int E, int N) {
  int i = blockIdx.x * blockDim.x + threadIdx.x;
  if (i >= E + N) return;
  int dst = (i < E) ? ei[E + i] : (i - E);
  atomicAdd(&deg[dst], 1);
}

__global__ __launch_bounds__(1024) void scan_block_kernel(const int* __restrict__ deg,
                                                          int* __restrict__ row_start,
                                                          int* __restrict__ sums, int n) {
  __shared__ int buf[1024];
  int t = threadIdx.x;
  int idx = blockIdx.x * 1024 + t;
  int x = (idx < n) ? deg[idx] : 0;
  int v = x;
  buf[t] = v;
  __syncthreads();
  for (int off = 1; off < 1024; off <<= 1) {
    int a = (t >= off) ? buf[t - off] : 0;
    __syncthreads();
    v += a;
    buf[t] = v;
    __syncthreads();
  }
  if (idx < n) row_start[idx] = v - x;  // local exclusive
  if (t == 1023) sums[blockIdx.x] = v;  // chunk total
}

__global__ __launch_bounds__(1024) void scan_sums_kernel(int* __restrict__ sums,
                                                         int* __restrict__ row_start,
                                                         int nch, int n) {
  __shared__ int buf[1024];
  int t = threadIdx.x;
  int x = (t < nch) ? sums[t] : 0;
  int v = x;
  buf[t] = v;
  __syncthreads();
  for (int off = 1; off < 1024; off <<= 1) {
    int a = (t >= off) ? buf[t - off] : 0;
    __syncthreads();
    v += a;
    buf[t] = v;
    __syncthreads();
  }
  if (t < nch) sums[t] = v - x;        // exclusive chunk offsets
  if (t == 1023) row_start[n] = v;     // grand total
}

__global__ __launch_bounds__(1024) void scan_add_kernel(int* __restrict__ row_start,
                                                        const int* __restrict__ sums, int n) {
  int idx = blockIdx.x * 1024 + threadIdx.x;
  if (idx < n) row_start[idx] += sums[blockIdx.x];
}

__global__ void fill_kernel(const int* __restrict__ ei, int* __restrict__ cursor,
                            const int* __restrict__ row_start, int* __restrict__ csr_src,
                            int* __restrict__ csr_dst, int E, int N) {
  int i = blockIdx.x * blockDim.x + threadIdx.x;
  if (i >= E + N) return;
  int src, dst;
  if (i < E) { src = ei[i]; dst = ei[E + i]; } else { src = dst = i - E; }
  int pos = atomicAdd(&cursor[dst], 1);
  int slot = row_start[dst] + pos;
  csr_src[slot] = src;
  csr_dst[slot] = dst;
}

// ---------------------------------------------------------------- GEMM  Hb = bf16(X @ W), fused alpha dots
__global__ __launch_bounds__(256) void gemm_kernel(const float* __restrict__ X,
                                                   const float* __restrict__ W,
                                                   unsigned short* __restrict__ Hb,
                                                   const float* __restrict__ a_src,
                                                   const float* __restrict__ a_dst,
                                                   float* __restrict__ as_arr,
                                                   float* __restrict__ ad_arr,
                                                   int nrows, int K) {
  __shared__ float Xs[64][36];    // 64 rows x 32 k, stride 36
  __shared__ float Ws[32][132];   // 32 k x 128 cols, stride 132
  int t = threadIdx.x;
  int row0 = blockIdx.x * 64;
  int tcol = t & 31;   // 32 col-groups of 4 cols
  int trow = t >> 5;   // 8 row-groups; rows trow + 8*i
  float acc[8][4];
#pragma unroll
  for (int i = 0; i < 8; ++i)
#pragma unroll
    for (int j = 0; j < 4; ++j) acc[i][j] = 0.0f;

  for (int kb = 0; kb < K; kb += 32) {
#pragma unroll
    for (int p = 0; p < 2; ++p) {       // X tile: 64x32 = 512 float4
      int flat = t + p * 256;
      int r = flat >> 3;
      int kq = (flat & 7) * 4;
      float4 v = make_float4(0.f, 0.f, 0.f, 0.f);
      int gr = row0 + r;
      if (gr < nrows) v = *(const float4*)(X + (size_t)gr * K + kb + kq);
      *(float4*)(&Xs[r][kq]) = v;
    }
#pragma unroll
    for (int p = 0; p < 4; ++p) {       // W tile: 32x128 = 1024 float4
      int flat = t + p * 256;
      int r = flat >> 5;
      int cq = (flat & 31) * 4;
      float4 v = *(const float4*)(W + (size_t)(kb + r) * 128 + cq);
      *(float4*)(&Ws[r][cq]) = v;
    }
    __syncthreads();
#pragma unroll
    for (int kk = 0; kk < 32; kk += 4) {
      float4 xv[8];
#pragma unroll
      for (int i = 0; i < 8; ++i) xv[i] = *(const float4*)(&Xs[trow + 8 * i][kk]);
#pragma unroll
      for (int q = 0; q < 4; ++q) {
        float4 wv = *(const float4*)(&Ws[kk + q][tcol * 4]);
#pragma unroll
        for (int i = 0; i < 8; ++i) {
          float xq = (q == 0) ? xv[i].x : (q == 1) ? xv[i].y : (q == 2) ? xv[i].z : xv[i].w;
          acc[i][0] += xq * wv.x;
          acc[i][1] += xq * wv.y;
          acc[i][2] += xq * wv.z;
          acc[i][3] += xq * wv.w;
        }
      }
    }
    __syncthreads();
  }

  // store bf16 H + fused per-head alpha dots
  float4 as4 = *(const float4*)(a_src + tcol * 4);
  float4 ad4 = *(const float4*)(a_dst + tcol * 4);
  float ps[8], pd[8];
#pragma unroll
  for (int i = 0; i < 8; ++i) {
    int r = row0 + trow + 8 * i;
    if (r < nrows) {
      union { unsigned short u[4]; uint2 v; } pk;
      pk.u[0] = f2bf(acc[i][0]);
      pk.u[1] = f2bf(acc[i][1]);
      pk.u[2] = f2bf(acc[i][2]);
      pk.u[3] = f2bf(acc[i][3]);
      *(uint2*)(Hb + (size_t)r * 128 + tcol * 4) = pk.v;
    }
    ps[i] = acc[i][0] * as4.x + acc[i][1] * as4.y + acc[i][2] * as4.z + acc[i][3] * as4.w;
    pd[i] = acc[i][0] * ad4.x + acc[i][1] * ad4.y + acc[i][2] * ad4.z + acc[i][3] * ad4.w;
  }
#pragma unroll
  for (int off = 1; off < 8; off <<= 1) {
#pragma unroll
    for (int i = 0; i < 8; ++i) {
      ps[i] += __shfl_xor(ps[i], off);
      pd[i] += __shfl_xor(pd[i], off);
    }
  }
  if ((tcol & 7) == 0) {
    int head = tcol >> 3;
#pragma unroll
    for (int i = 0; i < 8; ++i) {
      int r = row0 + trow + 8 * i;
      if (r < nrows) {
        as_arr[(size_t)r * 4 + head] = ps[i];
        ad_arr[(size_t)r * 4 + head] = pd[i];
      }
    }
  }
}

// ---------------------------------------------------------------- per-edge exp(leaky(logit)) for all 4 heads
// edge-parallel: coalesced idx reads + e writes; alpha gathers are 16B random in
// an 800KB L2-resident array; no serial chains -> latency fully hidden by TLP.
__global__ __launch_bounds__(256) void ecomp_kernel(const int* __restrict__ csr_src,
                                                    const int* __restrict__ csr_dst,
                                                    const float* __restrict__ as_arr,
                                                    const float* __restrict__ ad_arr,
                                                    float* __restrict__ earr, int Etot) {
  int i = blockIdx.x * 256 + threadIdx.x;
  if (i >= Etot) return;
  int s = csr_src[i];
  int d = csr_dst[i];
  float4 a = *(const float4*)(as_arr + (size_t)s * 4);
  float4 b = *(const float4*)(ad_arr + (size_t)d * 4);
  float4 e;
  e.x = __expf(fminf(leaky(a.x + b.x), 80.f));
  e.y = __expf(fminf(leaky(a.y + b.y), 80.f));
  e.z = __expf(fminf(leaky(a.z + b.z), 80.f));
  e.w = __expf(fminf(leaky(a.w + b.w), 80.f));
  *(float4*)(earr + (size_t)i * 4) = e;
}

// ---------------------------------------------------------------- aggregation v5
// one wave per dst node (R2 shape); lane owns channels 2l,2l+1. Per iteration:
// sequential/broadcast loads of csr_src[i], earr[i] + ONE random 256B row gather.
// Unroll 4 -> 4 independent single-level gather chains per wave.
template <int POOL>
__global__ __launch_bounds__(256) void agg_kernel(const unsigned short* __restrict__ Hb,
                                                  const float* __restrict__ earr,
                                                  const int* __restrict__ csr_src,
                                                  const int* __restrict__ row_start,
                                                  const float* __restrict__ bias,
                                                  float* __restrict__ xnext,
                                                  const int* __restrict__ batch,
                                                  float* __restrict__ pooled, int N) {
  int wid = threadIdx.x >> 6;
  int lane = threadIdx.x & 63;
  int n = blockIdx.x * 4 + wid;
  if (n >= N) return;
  int rs = row_start[n], re = row_start[n + 1];
  int head = lane >> 4;

  const unsigned* hp = (const unsigned*)Hb + lane;  // lane owns packed channels 2l,2l+1
  const float* ep = earr + head;
  float denom = 0.f, acc0 = 0.f, acc1 = 0.f;
  int i = rs;
  for (; i + 4 <= re; i += 4) {
    int s0 = csr_src[i], s1 = csr_src[i + 1], s2 = csr_src[i + 2], s3 = csr_src[i + 3];
    float e0 = ep[(size_t)i * 4];
    float e1 = ep[(size_t)(i + 1) * 4];
    float e2 = ep[(size_t)(i + 2) * 4];
    float e3 = ep[(size_t)(i + 3) * 4];
    unsigned u0 = hp[(size_t)s0 * 64];
    unsigned u1 = hp[(size_t)s1 * 64];
    unsigned u2 = hp[(size_t)s2 * 64];
    unsigned u3 = hp[(size_t)s3 * 64];
    denom += (e0 + e1) + (e2 + e3);
    float2 f;
    f = bf2f2(u0); acc0 += e0 * f.x; acc1 += e0 * f.y;
    f = bf2f2(u1); acc0 += e1 * f.x; acc1 += e1 * f.y;
    f = bf2f2(u2); acc0 += e2 * f.x; acc1 += e2 * f.y;
    f = bf2f2(u3); acc0 += e3 * f.x; acc1 += e3 * f.y;
  }
  for (; i < re; ++i) {
    int s0 = csr_src[i];
    float e0 = ep[(size_t)i * 4];
    unsigned u0 = hp[(size_t)s0 * 64];
    float2 f = bf2f2(u0);
    denom += e0;
    acc0 += e0 * f.x;
    acc1 += e0 * f.y;
  }
  float inv = 1.0f / (denom + 1e-16f);
  float2 bv = *(const float2*)(bias + 2 * lane);
  float v0 = leaky(acc0 * inv + bv.x);
  float v1 = leaky(acc1 * inv + bv.y);
  if (POOL) {
    int g = batch[n];
    atomicAdd(&pooled[(size_t)g * 128 + 2 * lane], v0);
    atomicAdd(&pooled[(size_t)g * 128 + 2 * lane + 1], v1);
  } else {
    *(float2*)(xnext + (size_t)n * 128 + 2 * lane) = make_float2(v0, v1);
  }
}

// ---------------------------------------------------------------- head
__global__ void head_kernel(const float* __restrict__ pooled, const float* __restrict__ fc_w,
                            const float* __restrict__ fc_b, const float* __restrict__ bn_g,
                            const float* __restrict__ bn_b, float* __restrict__ out, int G) {
  int t = threadIdx.x;
  int g = blockIdx.x * 8 + (t >> 5);
  int j = t & 31;
  if (g >= G) return;
  const float* pr = pooled + (size_t)g * 128;
  float acc = 0.f;
#pragma unroll 8
  for (int k = 0; k < 128; ++k) acc += pr[k] * fc_w[k * 32 + j];
  const float inv = 0.9999950000374997f;  // 1/sqrt(1+1e-5)
  out[g * 32 + j] = bn_g[j] * (acc + fc_b[j]) * inv + bn_b[j];
}

// ---------------------------------------------------------------- launch
extern "C" void kernel_launch(void* const* d_in, const int* in_sizes, int n_in,
                              void* d_out, int out_size, void* d_ws, size_t ws_size,
                              hipStream_t stream) {
  const float* x = (const float*)d_in[0];
  const int* ei = (const int*)d_in[1];
  const int* batch = (const int*)d_in[2];
  const float* Wm[3] = {(const float*)d_in[3], (const float*)d_in[7], (const float*)d_in[11]};
  const float* a_s[3] = {(const float*)d_in[4], (const float*)d_in[8], (const float*)d_in[12]};
  const float* a_d[3] = {(const float*)d_in[5], (const float*)d_in[9], (const float*)d_in[13]};
  const float* bb[3] = {(const float*)d_in[6], (const float*)d_in[10], (const float*)d_in[14]};
  const float* fc_w = (const float*)d_in[15];
  const float* fc_b = (const float*)d_in[16];
  const float* bn_g = (const float*)d_in[17];
  const float* bn_b = (const float*)d_in[18];
  float* out = (float*)d_out;

  int N = in_sizes[0] / 64;
  int E = in_sizes[1] / 2;
  int G = out_size / 32;
  int Etot = E + N;

  char* p = (char*)d_ws;
  auto carve = [&](size_t bytes) {
    char* r = p;
    p += (bytes + 255) & ~size_t(255);
    return r;
  };
  int* deg       = (int*)carve((size_t)N * 4);
  int* cursor    = (int*)carve((size_t)N * 4);
  float* pooled  = (float*)carve((size_t)G * 128 * 4);
  int* row_start = (int*)carve((size_t)(N + 1) * 4);
  int* sums      = (int*)carve(4096);
  int* csr_src   = (int*)carve((size_t)Etot * 4);
  int* csr_dst   = (int*)carve((size_t)Etot * 4);
  float* earr    = (float*)carve((size_t)Etot * 4 * 4);              // per-edge exp, 4 heads
  unsigned short* Hb = (unsigned short*)carve((size_t)N * 128 * 2);  // bf16 features
  float* bufX    = (float*)carve((size_t)N * 128 * 4);               // fp32 layer input
  float* as_arr  = (float*)carve((size_t)N * 4 * 4);
  float* ad_arr  = (float*)carve((size_t)N * 4 * 4);

  // zero deg+cursor+pooled (contiguous carve region, pads included)
  int nz = (int)(((char*)(pooled + (size_t)G * 128) - (char*)deg) / 4);
  zero_kernel<<<512, 256, 0, stream>>>(deg, nz);

  // CSR build (dst-grouped)
  int egrid = (Etot + 255) / 256;
  count_kernel<<<egrid, 256, 0, stream>>>(ei, deg, E, N);
  int nch = (N + 1023) / 1024;
  scan_block_kernel<<<nch, 1024, 0, stream>>>(deg, row_start, sums, N);
  scan_sums_kernel<<<1, 1024, 0, stream>>>(sums, row_start, nch, N);
  scan_add_kernel<<<nch, 1024, 0, stream>>>(row_start, sums, N);
  fill_kernel<<<egrid, 256, 0, stream>>>(ei, cursor, row_start, csr_src, csr_dst, E, N);

  int ggrid = (N + 63) / 64;
  int ngrid = (N + 3) / 4;

  // layer 0 (K=64)
  gemm_kernel<<<ggrid, 256, 0, stream>>>(x, Wm[0], Hb, a_s[0], a_d[0], as_arr, ad_arr, N, 64);
  ecomp_kernel<<<egrid, 256, 0, stream>>>(csr_src, csr_dst, as_arr, ad_arr, earr, Etot);
  agg_kernel<0><<<ngrid, 256, 0, stream>>>(Hb, earr, csr_src, row_start, bb[0],
                                           bufX, nullptr, nullptr, N);
  // layer 1 (K=128)
  gemm_kernel<<<ggrid, 256, 0, stream>>>(bufX, Wm[1], Hb, a_s[1], a_d[1], as_arr, ad_arr, N, 128);
  ecomp_kernel<<<egrid, 256, 0, stream>>>(csr_src, csr_dst, as_arr, ad_arr, earr, Etot);
  agg_kernel<0><<<ngrid, 256, 0, stream>>>(Hb, earr, csr_src, row_start, bb[1],
                                           bufX, nullptr, nullptr, N);
  // layer 2 (K=128), fused pooling
  gemm_kernel<<<ggrid, 256, 0, stream>>>(bufX, Wm[2], Hb, a_s[2], a_d[2], as_arr, ad_arr, N, 128);
  ecomp_kernel<<<egrid, 256, 0, stream>>>(csr_src, csr_dst, as_arr, ad_arr, earr, Etot);
  agg_kernel<1><<<ngrid, 256, 0, stream>>>(Hb, earr, csr_src, row_start, bb[2],
                                           nullptr, batch, pooled, N);

  head_kernel<<<(G + 7) / 8, 256, 0, stream>>>(pooled, fc_w, fc_b, bn_g, bn_b, out, G);
}